// Round 4
// baseline (292.491 us; speedup 1.0000x reference)
//
#include <hip/hip_runtime.h>

// Problem constants (from reference):
//   D = 8388608 elements, N = M = 1024 (power of two -> mod == AND)
// Outputs concatenated in d_out (float32):
//   [0,      D)      phase_out  (as float)
//   [D,     2D)      mag_out    (as float)
//   [2D,    3D)      signal
//   [3D]             strength   (scalar)
//   [3D+1,  4D+1)    grad_phase   <- section base misaligned by 4B
//   [4D+1,  5D+1)    grad_mag     <- same
//
// Two-kernel design (kept): main writes 5 streams + per-tile partials to
// d_ws; 1-block kernel reduces. Fused atomic variant regressed 5x. Never.
//
// Optimization history (main kernel time):
//  R0  ~87us: 4096 short blocks, all regular stores, misaligned f32x8 grads.
//  R1  116us: all-nontemporal. WRITE 297.6 vs 167.8 MB mandatory -- nt
//      defeats L2 write-merging (partial 32B sectors go to HBM as-is).
//  R2  107us: nt only po/mo/sig. WRITE 220 MB. Every nt stream costs. Revert.
//  R3  ~88us: 32B-aligned grad stores via slot-shift + shfl. NEUTRAL vs R0
//      -> no partial-line RMW penalty existed. Alignment is not a lever.
//  R4 (this): main moves ~300 MB in 88us = 3.4 TB/s while the harness fill
//      does 6.75 TB/s at 9.5% occupancy on the same buffer. Nothing is busy
//      (VALU 4.5%, conflicts negligible, traffic mandatory) -> the gap is
//      device-wide phase-bunching: 4096 one-shot blocks in ~3 lockstep
//      generations alternate {stage, barrier, load-burst, LDS-gather
//      (memory idle), store-burst}. Fix: 2048 persistent blocks x 2 tiles,
//      stage tables ONCE, and pipeline: tile0 loads issue before staging,
//      tile1 loads issue right after the barrier so HBM reads overlap
//      tile0's gather+store phase. Reduction topology bitwise-preserved
//      (per-tile partial -> same 4096-entry block_sums array).
constexpr int D_TOTAL = 8388608;
constexpr int TBL = 1024;
constexpr int IDX_MASK = 1023;
constexpr int BLOCK = 256;
constexpr int VEC = 8;                              // elements per thread
constexpr int ELEMS_PER_TILE = BLOCK * VEC;         // 2048
constexpr int NTILES = D_TOTAL / ELEMS_PER_TILE;    // 4096 partial sums
constexpr int TPB = 2;                              // tiles per block
constexpr int NBLOCKS_MAIN = NTILES / TPB;          // 2048

typedef float f32x4 __attribute__((ext_vector_type(4)));
typedef float f32x8 __attribute__((ext_vector_type(8)));
typedef int   i32x8 __attribute__((ext_vector_type(8)));
// Grad sections start at 3D+1/4D+1 (4B off 32B). aligned(4) f32x8 makes
// clang emit paired global_store_dwordx4 (dword alignment is all HW needs).
// R3 proved alignment-shifting these stores is perf-neutral; keep simple.
typedef f32x8 f32x8u __attribute__((aligned(4)));

__device__ __forceinline__ float process_tile(
    int base, i32x8 cp, i32x8 cm, i32x8 sp, i32x8 sm,
    const float2* __restrict__ s_phase, const float2* __restrict__ s_mag,
    float* __restrict__ out) {
  int p[VEC], m[VEC];
#pragma unroll
  for (int j = 0; j < VEC; ++j) {
    p[j] = (cp[j] + sp[j]) & IDX_MASK;
    m[j] = (cm[j] + sm[j]) & IDX_MASK;
  }
  f32x8 po, mo, sg;
  f32x8u gp, gm;
  float local = 0.f;
  // Accumulation order over j=0..7 IDENTICAL to all verified rounds
  // (strength bitwise-stable, absmax 0.0 four rounds running).
#pragma unroll
  for (int j = 0; j < VEC; ++j) {
    const float2 ph = s_phase[p[j]];
    const float2 mg = s_mag[m[j]];
    const float s = ph.x * mg.x;
    sg[j] = s;
    gp[j] = ph.y * mg.x;
    gm[j] = ph.x * mg.y;
    po[j] = (float)p[j];
    mo[j] = (float)m[j];
    local += s;
  }
  // All regular stores (R1/R2 lesson: nt costs +50..130 MB WRITE_SIZE).
  *reinterpret_cast<f32x8*>(out + base)                     = po;
  *reinterpret_cast<f32x8*>(out + D_TOTAL + base)           = mo;
  *reinterpret_cast<f32x8*>(out + 2 * D_TOTAL + base)       = sg;
  *reinterpret_cast<f32x8u*>(out + 3 * D_TOTAL + 1 + base)  = gp;
  *reinterpret_cast<f32x8u*>(out + 4 * D_TOTAL + 1 + base)  = gm;
  return local;
}

__global__ __launch_bounds__(BLOCK) void phasecell_main(
    const int* __restrict__ ctx_p, const int* __restrict__ ctx_m,
    const int* __restrict__ self_p, const int* __restrict__ self_m,
    const float* __restrict__ cos_t, const float* __restrict__ exp_t,
    const float* __restrict__ dcos_t, const float* __restrict__ dexp_t,
    float* __restrict__ out, float* __restrict__ block_sums) {
  const int base0 = (blockIdx.x * TPB) * ELEMS_PER_TILE + threadIdx.x * VEC;
  const int base1 = base0 + ELEMS_PER_TILE;

  // Tile0 idx loads FIRST: ~900-cycle HBM latency hides under table staging
  // + the barrier.
  const i32x8 cp0 = *reinterpret_cast<const i32x8*>(ctx_p + base0);
  const i32x8 cm0 = *reinterpret_cast<const i32x8*>(ctx_m + base0);
  const i32x8 sp0 = *reinterpret_cast<const i32x8*>(self_p + base0);
  const i32x8 sm0 = *reinterpret_cast<const i32x8*>(self_m + base0);

  // Stage interleaved tables in LDS once per block (was: once per tile).
  __shared__ float2 s_phase[TBL];  // (cos, dcos)
  __shared__ float2 s_mag[TBL];    // (exp, dexp)
  for (int i = threadIdx.x; i < TBL; i += BLOCK) {
    s_phase[i] = make_float2(cos_t[i], dcos_t[i]);
    s_mag[i]   = make_float2(exp_t[i], dexp_t[i]);
  }
  __syncthreads();

  // Tile1 idx loads issue NOW: their latency hides under tile0's
  // gather+store phase, keeping the read path busy while LDS is in use.
  const i32x8 cp1 = *reinterpret_cast<const i32x8*>(ctx_p + base1);
  const i32x8 cm1 = *reinterpret_cast<const i32x8*>(ctx_m + base1);
  const i32x8 sp1 = *reinterpret_cast<const i32x8*>(self_p + base1);
  const i32x8 sm1 = *reinterpret_cast<const i32x8*>(self_m + base1);

  __shared__ float wsum[TPB][BLOCK / 64];
  const int wave = threadIdx.x >> 6;
  const int lane = threadIdx.x & 63;

  // ---- tile 0
  float r0 = process_tile(base0, cp0, cm0, sp0, sm0, s_phase, s_mag, out);
#pragma unroll
  for (int off = 32; off > 0; off >>= 1) r0 += __shfl_down(r0, off, 64);
  if (lane == 0) wsum[0][wave] = r0;

  // ---- tile 1
  float r1 = process_tile(base1, cp1, cm1, sp1, sm1, s_phase, s_mag, out);
#pragma unroll
  for (int off = 32; off > 0; off >>= 1) r1 += __shfl_down(r1, off, 64);
  if (lane == 0) wsum[1][wave] = r1;

  __syncthreads();
  if (threadIdx.x == 0) {
    // Same per-tile 4-wave sequential sum and same block_sums indexing as
    // every verified round -> reduce kernel input is bitwise identical.
    float t0 = 0.f, t1 = 0.f;
#pragma unroll
    for (int w = 0; w < BLOCK / 64; ++w) t0 += wsum[0][w];
#pragma unroll
    for (int w = 0; w < BLOCK / 64; ++w) t1 += wsum[1][w];
    block_sums[blockIdx.x * TPB]     = t0;
    block_sums[blockIdx.x * TPB + 1] = t1;
  }
}

__global__ __launch_bounds__(BLOCK) void phasecell_reduce(
    const float* __restrict__ partials, float* __restrict__ strength_out) {
  float s = 0.f;
  for (int i = threadIdx.x; i < NTILES; i += BLOCK) s += partials[i];
#pragma unroll
  for (int off = 32; off > 0; off >>= 1) s += __shfl_down(s, off, 64);
  __shared__ float wsum[BLOCK / 64];
  const int wave = threadIdx.x >> 6;
  const int lane = threadIdx.x & 63;
  if (lane == 0) wsum[wave] = s;
  __syncthreads();
  if (threadIdx.x == 0) {
    float t = 0.f;
#pragma unroll
    for (int w = 0; w < BLOCK / 64; ++w) t += wsum[w];
    strength_out[0] = t;  // out[3D]
  }
}

extern "C" void kernel_launch(void* const* d_in, const int* in_sizes, int n_in,
                              void* d_out, int out_size, void* d_ws, size_t ws_size,
                              hipStream_t stream) {
  const int* ctx_p  = (const int*)d_in[0];
  const int* ctx_m  = (const int*)d_in[1];
  const int* self_p = (const int*)d_in[2];
  const int* self_m = (const int*)d_in[3];
  const float* cos_t  = (const float*)d_in[4];
  const float* exp_t  = (const float*)d_in[5];
  const float* dcos_t = (const float*)d_in[6];
  const float* dexp_t = (const float*)d_in[7];
  float* out = (float*)d_out;
  float* block_sums = (float*)d_ws;  // NTILES floats = 16 KB

  phasecell_main<<<NBLOCKS_MAIN, BLOCK, 0, stream>>>(
      ctx_p, ctx_m, self_p, self_m, cos_t, exp_t, dcos_t, dexp_t, out, block_sums);
  phasecell_reduce<<<1, BLOCK, 0, stream>>>(block_sums, out + 3 * (size_t)D_TOTAL);
}